// Round 9
// baseline (534.918 us; speedup 1.0000x reference)
//
#include <hip/hip_runtime.h>
#include <math.h>

#define NB 4
#define NL 1024
#define ND 1024
#define NH 16
#define HD 64

typedef __attribute__((ext_vector_type(8))) short bf16x8;
typedef __attribute__((ext_vector_type(4))) float f32x4;
typedef __attribute__((ext_vector_type(16))) float f32x16;

static __device__ __forceinline__ unsigned short f32_to_bf16(float f) {
  unsigned u = __float_as_uint(f);
  u += 0x7FFFu + ((u >> 16) & 1u);   // RNE
  return (unsigned short)(u >> 16);
}
static __device__ __forceinline__ float bf16_to_f32(unsigned short s) {
  return __uint_as_float(((unsigned)s) << 16);
}
// trunc-split: x = hi + lo + O(2^-17 |x|)
static __device__ __forceinline__ void split1(float x, unsigned short* h, unsigned short* l) {
  unsigned u = __float_as_uint(x);
  *h = (unsigned short)(u >> 16);
  float r = x - __uint_as_float(u & 0xFFFF0000u);
  *l = (unsigned short)(__float_as_uint(r) >> 16);
}
static __device__ __forceinline__ void split8(float4 a, float4 b, bf16x8* hi, bf16x8* lo) {
  unsigned u[8] = {__float_as_uint(a.x), __float_as_uint(a.y),
                   __float_as_uint(a.z), __float_as_uint(a.w),
                   __float_as_uint(b.x), __float_as_uint(b.y),
                   __float_as_uint(b.z), __float_as_uint(b.w)};
  union { unsigned p[4]; bf16x8 v; } H, L;
#pragma unroll
  for (int p = 0; p < 4; ++p) {
    unsigned u0 = u[2 * p], u1 = u[2 * p + 1];
    H.p[p] = __builtin_amdgcn_perm(u1, u0, 0x07060302u);
    unsigned l0 = __float_as_uint(__uint_as_float(u0) - __uint_as_float(u0 & 0xFFFF0000u));
    unsigned l1 = __float_as_uint(__uint_as_float(u1) - __uint_as_float(u1 & 0xFFFF0000u));
    L.p[p] = __builtin_amdgcn_perm(l1, l0, 0x07060302u);
  }
  *hi = H.v; *lo = L.v;
}

// ---------------- weight convert: w[o][i][k] -> Wb hi/lo [koff][o][i] bf16 ----------------
__global__ __launch_bounds__(256) void wcvt_kernel(
    const float* __restrict__ w0, const float* __restrict__ w1,
    const float* __restrict__ w2, const float* __restrict__ w3,
    unsigned short* __restrict__ wb, int* __restrict__ flag)
{
  if (blockIdx.x == 0 && blockIdx.y == 0 && threadIdx.x == 0) flag[0] = 0;
  const int t = blockIdx.y;
  const int o = blockIdx.x;
  const float* w = (t == 0) ? w0 : (t == 1) ? w1 : (t == 2) ? w2 : w3;
  unsigned short* hi = wb + (size_t)t * 6 * (1u << 20);
  unsigned short* lo = hi + 3 * (1u << 20);
  const int tid = threadIdx.x;
  float v[12];
  const float* src = w + (size_t)o * (ND * 3) + tid * 12;
#pragma unroll
  for (int j = 0; j < 3; ++j) {
    float4 f = *(const float4*)(src + j * 4);
    v[j * 4 + 0] = f.x; v[j * 4 + 1] = f.y; v[j * 4 + 2] = f.z; v[j * 4 + 3] = f.w;
  }
#pragma unroll
  for (int k = 0; k < 3; ++k) {
    unsigned short hh[4], ll[4];
#pragma unroll
    for (int ii = 0; ii < 4; ++ii) {
      float x = v[ii * 3 + k];
      unsigned short h = f32_to_bf16(x);
      float r = x - bf16_to_f32(h);
      hh[ii] = h; ll[ii] = f32_to_bf16(r);
    }
    size_t dst = (size_t)k * (ND * ND) + (size_t)o * ND + tid * 4;
    *(ushort4*)&hi[dst] = make_ushort4(hh[0], hh[1], hh[2], hh[3]);
    *(ushort4*)&lo[dst] = make_ushort4(ll[0], ll[1], ll[2], ll[3]);
  }
}

// ---------------- amask zero-scan ----------------
__global__ __launch_bounds__(256) void amask_scan(
    const float* __restrict__ a, int* __restrict__ flag)
{
  size_t i = ((size_t)blockIdx.x * 256 + threadIdx.x) * 4;
  float4 v = *(const float4*)&a[i];
  if (v.x != 0.f || v.y != 0.f || v.z != 0.f || v.w != 0.f) atomicOr(flag, 1);
}

// ---------------- conv-as-GEMM: R5 loop structure + 32x32x16 MFMA ----------------
// MODE 0: z = tensor (q/k/v), koff 0..2; A = fp32 inputs (clamp + edge-fix);
//         epilogue writes split bf16 q(scaled)/k, bf16 v  [B,H,L,HD]
// MODE 1: z = koff (split-K o-conv); A = fp32 padded AO [B,1026,D]; fp32 partials P[z]
template <int MODE>
__global__ __launch_bounds__(256, 3) void conv_mfma6(
    const float* __restrict__ X0, const float* __restrict__ X1,
    const float* __restrict__ X2,
    const unsigned short* __restrict__ wb,
    const float* b0, const float* b1, const float* b2,
    unsigned short* qh, unsigned short* ql,
    unsigned short* kh, unsigned short* kl, unsigned short* vv,
    float* P)
{
  __shared__ __align__(16) float Af[4096];            // 16KB fp32 A tile
  __shared__ __align__(16) unsigned short Bh[4096];   // 8KB
  __shared__ __align__(16) unsigned short Bl[4096];   // 8KB

  const int tid = threadIdx.x, lane = tid & 63, wave = tid >> 6;
  const int lin = blockIdx.x + 8 * (blockIdx.y + 32 * blockIdx.z);
  const int g = lin & 7, t = lin >> 3;
  const int nb = (g & 3) * 2 + (t & 1);
  const int mb = (g >> 2) * 16 + ((t >> 1) & 15);
  const int z  = t >> 5;
  const int n0 = nb * 128, m0 = mb * 128;
  const int b = m0 >> 10, l0v = m0 & (NL - 1);

  const unsigned short* Wh = (MODE == 0) ? wb + (size_t)z * 6 * (1u << 20) : wb;
  const unsigned short* Wl = Wh + 3 * (1u << 20);
  const float* X = (MODE == 0) ? (z == 0 ? X0 : (z == 1 ? X1 : X2)) : X0;

  const int wm2 = (wave >> 1) * 64, wn2 = (wave & 1) * 64;
  const int ln31 = lane & 31, khalf = lane >> 5;
  const int r16 = lane >> 2, cs = lane & 3;
  const int src_chunk = (cs - (r16 >> 1)) & 3;      // B global-side granule swizzle

  f32x16 acc[2][2] = {};
  const int NS = (MODE == 0) ? 96 : 32;             // (koff) x (i0/32)

  // ---- staging (async global->LDS) for step s — identical to R5 ----
  auto stage = [&](int s) {
    const int koff = (MODE == 0) ? (s >> 5) : z;
    const int i0 = (s & 31) * 32;
#pragma unroll
    for (int j = 0; j < 2; ++j) {
      const int seg = wave * 2 + j;
      const size_t gw = ((size_t)koff << 20) +
                        (size_t)(n0 + seg * 16 + r16) * ND + i0 + src_chunk * 8;
      __builtin_amdgcn_global_load_lds(
          (const __attribute__((address_space(1))) unsigned int*)(Wh + gw),
          (__attribute__((address_space(3))) unsigned int*)&Bh[seg * 512], 16, 0, 0);
      __builtin_amdgcn_global_load_lds(
          (const __attribute__((address_space(1))) unsigned int*)(Wl + gw),
          (__attribute__((address_space(3))) unsigned int*)&Bl[seg * 512], 16, 0, 0);
    }
#pragma unroll
    for (int j = 0; j < 4; ++j) {
      const int sl = (wave * 4 + j) * 64 + lane;
      const int row = sl >> 3, sir = sl & 7;
      const int chunk = (sir - (row & 7)) & 7;
      const float* gp;
      if (MODE == 0) {
        int l = l0v + row + koff - 1;
        l = (l < 0) ? 0 : (l > NL - 1 ? NL - 1 : l);   // clamp; edge zero-fix below
        gp = X + ((size_t)(b << 10) + l) * ND + i0 + chunk * 4;
      } else {
        gp = X + (size_t)(b * 1026 + l0v + z + row) * ND + i0 + chunk * 4;
      }
      __builtin_amdgcn_global_load_lds(
          (const __attribute__((address_space(1))) unsigned int*)gp,
          (__attribute__((address_space(3))) unsigned int*)&Af[(wave * 4 + j) * 256],
          16, 0, 0);
    }
  };

  auto edgefix = [&](int s) {
    if (MODE == 0) {
      const int koff = s >> 5;
      const bool e_lo = (l0v == 0 && koff == 0);
      const bool e_hi = (l0v == NL - 128 && koff == 2);
      if (e_lo || e_hi) {                 // block-uniform; 2 blocks per z only
        const int er = e_lo ? 0 : 127;
        if (tid < 8) *(float4*)&Af[er * 32 + tid * 4] = make_float4(0.f, 0.f, 0.f, 0.f);
        __syncthreads();
      }
    }
  };

  for (int s = 0; s < NS; ++s) {
    stage(s);
    __syncthreads();
    edgefix(s);

    // ---- A fragments: A[m=ln31][k=khalf*8+j], fp32 -> split hi/lo ----
    bf16x8 ah[2][2], al[2][2];   // [mf][kstep]
#pragma unroll
    for (int mf = 0; mf < 2; ++mf) {
      const int row = wm2 + mf * 32 + ln31, r7 = row & 7;
#pragma unroll
      for (int ts = 0; ts < 2; ++ts) {
        const int c0 = ts * 4 + khalf * 2;
        float4 fa = *(const float4*)&Af[row * 32 + (((c0 + 0) + r7) & 7) * 4];
        float4 fb = *(const float4*)&Af[row * 32 + (((c0 + 1) + r7) & 7) * 4];
        split8(fa, fb, &ah[mf][ts], &al[mf][ts]);
      }
    }
    // ---- B fragments + MFMA: 24 x v_mfma_f32_32x32x16_bf16 / wave / step ----
#pragma unroll
    for (int ts = 0; ts < 2; ++ts)
#pragma unroll
      for (int nf = 0; nf < 2; ++nf) {
        const int brow = wn2 + nf * 32 + ln31;
        const int slot = ((ts * 2 + khalf) + ((brow & 15) >> 1)) & 3;
        bf16x8 bhf = *(const bf16x8*)&Bh[brow * 32 + slot * 8];
        bf16x8 blf = *(const bf16x8*)&Bl[brow * 32 + slot * 8];
#pragma unroll
        for (int mf = 0; mf < 2; ++mf) {
          acc[mf][nf] = __builtin_amdgcn_mfma_f32_32x32x16_bf16(ah[mf][ts], bhf, acc[mf][nf], 0, 0, 0);
          acc[mf][nf] = __builtin_amdgcn_mfma_f32_32x32x16_bf16(ah[mf][ts], blf, acc[mf][nf], 0, 0, 0);
          acc[mf][nf] = __builtin_amdgcn_mfma_f32_32x32x16_bf16(al[mf][ts], bhf, acc[mf][nf], 0, 0, 0);
        }
      }
    __syncthreads();
  }

  // ---- epilogue: C/D 32x32 layout col=lane&31 (n), row=(reg&3)+8*(reg>>2)+4*khalf (m) ----
  if (MODE == 0) {
    const float* bias = (z == 0) ? b0 : (z == 1) ? b1 : b2;
#pragma unroll
    for (int nf = 0; nf < 2; ++nf) {
      const int n = n0 + wn2 + nf * 32 + ln31;
      const float bv = bias[n];
      const int h2 = n >> 6, dd = n & 63;
#pragma unroll
      for (int mf = 0; mf < 2; ++mf) {
        f32x16 v = acc[mf][nf];
#pragma unroll
        for (int reg = 0; reg < 16; ++reg) {
          const int mloc = (reg & 3) + 8 * (reg >> 2) + 4 * khalf;
          const int l = l0v + wm2 + mf * 32 + mloc;
          const size_t o = (((size_t)b * NH + h2) * NL + l) * HD + dd;
          float val = v[reg] + bv;
          if (z == 0) {
            val *= 0.125f;
            unsigned short hs, ls; split1(val, &hs, &ls);
            qh[o] = hs; ql[o] = ls;
          } else if (z == 1) {
            unsigned short hs, ls; split1(val, &hs, &ls);
            kh[o] = hs; kl[o] = ls;
          } else {
            vv[o] = f32_to_bf16(val);
          }
        }
      }
    }
  } else {
    float* Pz = P + (size_t)z * ((size_t)NB * NL * ND);
#pragma unroll
    for (int nf = 0; nf < 2; ++nf) {
      const int n = n0 + wn2 + nf * 32 + ln31;
#pragma unroll
      for (int mf = 0; mf < 2; ++mf) {
        f32x16 v = acc[mf][nf];
#pragma unroll
        for (int reg = 0; reg < 16; ++reg) {
          const int mloc = (reg & 3) + 8 * (reg >> 2) + 4 * khalf;
          const int l = l0v + wm2 + mf * 32 + mloc;
          Pz[((size_t)(b << 10) + l) * ND + n] = v[reg];
        }
      }
    }
  }
}

// ---------------- reduce: out = P0 + P1 + P2 + bias ----------------
__global__ __launch_bounds__(256) void reduce_kernel(
    const float* __restrict__ P, const float* __restrict__ bias, float* __restrict__ out)
{
  const size_t S = (size_t)NB * NL * ND;
  const size_t idx = ((size_t)blockIdx.x * 256 + threadIdx.x) * 4;
  const int n = (int)(idx & (ND - 1));
  float4 p0 = *(const float4*)&P[idx];
  float4 p1 = *(const float4*)&P[idx + S];
  float4 p2 = *(const float4*)&P[idx + 2 * S];
  float4 bv = *(const float4*)&bias[n];
  float4 r;
  r.x = p0.x + p1.x + p2.x + bv.x;
  r.y = p0.y + p1.y + p2.y + bv.y;
  r.z = p0.z + p1.z + p2.z + bv.z;
  r.w = p0.w + p1.w + p2.w + bv.w;
  *(float4*)&out[idx] = r;
}

// ---------------- MFMA flash attention (writes fp32 padded AO) — unchanged ----------------
__global__ __launch_bounds__(256, 3) void attn_mfma3(
    const unsigned short* __restrict__ qhp, const unsigned short* __restrict__ qlp,
    const unsigned short* __restrict__ khp, const unsigned short* __restrict__ klp,
    const unsigned short* __restrict__ vvp, const int* __restrict__ kpm,
    const float* __restrict__ amask, const int* __restrict__ aflagp,
    float* __restrict__ AO)
{
  __shared__ __align__(16) unsigned short SM[8192 + 4608];  // Kh | Kl | Vt
  unsigned short* Kh = SM;
  unsigned short* Kl = SM + 4096;
  unsigned short* Vt = SM + 8192;

  const int tid = threadIdx.x, lane = tid & 63, wave = tid >> 6;
  const int c = lane & 15, quad = lane >> 4;
  const int lin = blockIdx.x;
  const int bh_ = (lin & 7) + 8 * (lin >> 7);
  const int mt = (lin >> 3) & 15;
  const int b = bh_ >> 4, h = bh_ & 15;
  const int m0 = mt * 64;
  const size_t base = (size_t)bh_ * (NL * HD);
  const int aflag = *aflagp;
  const int mrow = wave * 16 + c;
  const int gm = m0 + mrow;

  if (h == 0 && mt == 0)
    *(float4*)&AO[(size_t)(b * 1026) * ND + tid * 4] = make_float4(0.f, 0.f, 0.f, 0.f);
  if (h == 0 && mt == 15)
    *(float4*)&AO[((size_t)(b * 1026) + 1025) * ND + tid * 4] = make_float4(0.f, 0.f, 0.f, 0.f);

  const int rowo = lane >> 3;
  const int grano = ((lane & 7) - rowo) & 7;

#pragma unroll
  for (int j = 0; j < 2; ++j) {
    const int s = wave * 2 + j;
    const size_t go = base + (size_t)(m0 + s * 8 + rowo) * HD + grano * 8;
    __builtin_amdgcn_global_load_lds(
        (const __attribute__((address_space(1))) unsigned int*)(qhp + go),
        (__attribute__((address_space(3))) unsigned int*)&Kh[s * 512], 16, 0, 0);
    __builtin_amdgcn_global_load_lds(
        (const __attribute__((address_space(1))) unsigned int*)(qlp + go),
        (__attribute__((address_space(3))) unsigned int*)&Kl[s * 512], 16, 0, 0);
  }
  __syncthreads();
  bf16x8 qbh[2], qbl[2];
#pragma unroll
  for (int kb = 0; kb < 2; ++kb) {
    const int cso = ((kb * 4 + quad + mrow) & 7) * 8;
    qbh[kb] = *(const bf16x8*)&Kh[mrow * 64 + cso];
    qbl[kb] = *(const bf16x8*)&Kl[mrow * 64 + cso];
  }

  f32x4 acc[4] = {};
  float m_r = -INFINITY, l_r = 0.0f;
  const int sr = tid >> 2, scq = tid & 3;

  for (int n0t = 0; n0t < NL; n0t += 64) {
    __syncthreads();

    float mval[4][4];
#pragma unroll
    for (int nf = 0; nf < 4; ++nf) {
      int4 pm4 = *(const int4*)&kpm[b * NL + n0t + nf * 16 + quad * 4];
      const int* pmi = &pm4.x;
#pragma unroll
      for (int r = 0; r < 4; ++r) {
        float am = 0.f;
        if (aflag) am = amask[(size_t)gm * NL + (n0t + nf * 16 + quad * 4 + r)];
        mval[nf][r] = pmi[r] ? -INFINITY : am;
      }
    }

#pragma unroll
    for (int j = 0; j < 2; ++j) {
      const int s = wave * 2 + j;
      const size_t go = base + (size_t)(n0t + s * 8 + rowo) * HD + grano * 8;
      __builtin_amdgcn_global_load_lds(
          (const __attribute__((address_space(1))) unsigned int*)(khp + go),
          (__attribute__((address_space(3))) unsigned int*)&Kh[s * 512], 16, 0, 0);
      __builtin_amdgcn_global_load_lds(
          (const __attribute__((address_space(1))) unsigned int*)(klp + go),
          (__attribute__((address_space(3))) unsigned int*)&Kl[s * 512], 16, 0, 0);
    }
#pragma unroll
    for (int ii = 0; ii < 2; ++ii) {
      const int c8 = scq * 2 + ii;
      uint4 u = *(const uint4*)(vvp + base + (size_t)(n0t + sr) * HD + c8 * 8);
      const unsigned short* pe = (const unsigned short*)&u;
#pragma unroll
      for (int e = 0; e < 8; ++e) {
        const int dd = c8 * 8 + e;
        Vt[dd * 72 + (((sr >> 3) + dd) & 7) * 8 + (sr & 7)] = pe[e];
      }
    }
    __syncthreads();

    f32x4 sa[4] = {};
#pragma unroll
    for (int kb = 0; kb < 2; ++kb)
#pragma unroll
      for (int nf = 0; nf < 4; ++nf) {
        const int row = nf * 16 + c;
        const int cso = ((kb * 4 + quad + row) & 7) * 8;
        bf16x8 kah = *(const bf16x8*)&Kh[row * 64 + cso];
        bf16x8 kal = *(const bf16x8*)&Kl[row * 64 + cso];
        sa[nf] = __builtin_amdgcn_mfma_f32_16x16x32_bf16(kah, qbh[kb], sa[nf], 0, 0, 0);
        sa[nf] = __builtin_amdgcn_mfma_f32_16x16x32_bf16(kah, qbl[kb], sa[nf], 0, 0, 0);
        sa[nf] = __builtin_amdgcn_mfma_f32_16x16x32_bf16(kal, qbh[kb], sa[nf], 0, 0, 0);
      }

    float p[4][4];
    float tmax = -INFINITY;
#pragma unroll
    for (int nf = 0; nf < 4; ++nf)
#pragma unroll
      for (int r = 0; r < 4; ++r) {
        float s = sa[nf][r] + mval[nf][r];
        p[nf][r] = s;
        tmax = fmaxf(tmax, s);
      }
    tmax = fmaxf(tmax, __shfl_xor(tmax, 16));
    tmax = fmaxf(tmax, __shfl_xor(tmax, 32));
    const float newm = fmaxf(m_r, tmax);
    const float msafe = (newm == -INFINITY) ? 0.f : newm;
    const float alpha = __expf(m_r - msafe);
    float rs = 0.f;
#pragma unroll
    for (int nf = 0; nf < 4; ++nf)
#pragma unroll
      for (int r = 0; r < 4; ++r) {
        float e = __expf(p[nf][r] - msafe);
        p[nf][r] = e;
        rs += e;
      }
    rs += __shfl_xor(rs, 16);
    rs += __shfl_xor(rs, 32);
    l_r = l_r * alpha + rs;
    m_r = newm;
#pragma unroll
    for (int df = 0; df < 4; ++df) {
      acc[df][0] *= alpha; acc[df][1] *= alpha;
      acc[df][2] *= alpha; acc[df][3] *= alpha;
    }

    unsigned q16[4][2];
#pragma unroll
    for (int nf = 0; nf < 4; ++nf)
#pragma unroll
      for (int w = 0; w < 2; ++w)
        q16[nf][w] = (unsigned)f32_to_bf16(p[nf][2 * w]) |
                     ((unsigned)f32_to_bf16(p[nf][2 * w + 1]) << 16);
#pragma unroll
    for (int kb = 0; kb < 2; ++kb) {
      union { unsigned d[4]; bf16x8 v; } pb;
#pragma unroll
      for (int w = 0; w < 4; ++w) {
        const int addr = ((((quad & 1) * 2 + (w >> 1)) * 16 + c) << 2);
        unsigned v0 = __builtin_amdgcn_ds_bpermute(addr, (int)q16[2 * kb][w & 1]);
        unsigned v1 = __builtin_amdgcn_ds_bpermute(addr, (int)q16[2 * kb + 1][w & 1]);
        pb.d[w] = (quad >> 1) ? v1 : v0;
      }
#pragma unroll
      for (int df = 0; df < 4; ++df) {
        const int row = df * 16 + c;
        const int cso = ((kb * 4 + quad + row) & 7) * 8;
        bf16x8 va = *(const bf16x8*)&Vt[row * 72 + cso];
        acc[df] = __builtin_amdgcn_mfma_f32_16x16x32_bf16(va, pb.v, acc[df], 0, 0, 0);
      }
    }
  }

  __syncthreads();
  const float inv = 1.0f / l_r;
  float* Ob = (float*)SM + wave * (16 * 68);
#pragma unroll
  for (int df = 0; df < 4; ++df)
#pragma unroll
    for (int r = 0; r < 4; ++r)
      Ob[c * 68 + df * 16 + quad * 4 + r] = acc[df][r] * inv;
  __syncthreads();
  const int mr2 = lane >> 2, cq2 = lane & 3;
#pragma unroll
  for (int ii = 0; ii < 4; ++ii) {
    const int chunk = cq2 * 4 + ii;
    float4 v = *(const float4*)&Ob[mr2 * 68 + chunk * 4];
    *(float4*)&AO[((size_t)(b * 1026) + (m0 + wave * 16 + mr2) + 1) * ND +
                  h * HD + chunk * 4] = v;
  }
}

// ---------------- launch ----------------
extern "C" void kernel_launch(void* const* d_in, const int* in_sizes, int n_in,
                              void* d_out, int out_size, void* d_ws, size_t ws_size,
                              hipStream_t stream) {
  (void)in_sizes; (void)n_in; (void)out_size; (void)ws_size;
  const float* query = (const float*)d_in[0];
  const float* key_  = (const float*)d_in[1];
  const float* value = (const float*)d_in[2];
  const int*   kpm   = (const int*)d_in[3];
  const float* amask = (const float*)d_in[4];
  const float* q_w = (const float*)d_in[5];
  const float* q_b = (const float*)d_in[6];
  const float* k_w = (const float*)d_in[7];
  const float* k_b = (const float*)d_in[8];
  const float* v_w = (const float*)d_in[9];
  const float* v_b = (const float*)d_in[10];
  const float* o_w = (const float*)d_in[11];
  const float* o_b = (const float*)d_in[12];
  float* out = (float*)d_out;

  // ws layout (max offset 100.66 MB, proven since R1):
  //  [0, 50.33M): Wb (4 tensors hi/lo bf16)
  //  [50.33M, 92.27M): qh/ql/kh/kl/vv bf16 (dead after attn)
  //  AO fp32 padded [B,1026,D] at [0, 16.81M) over dead Wb q/k slabs (Wb_o untouched)
  //  P fp32 [50.33M, 100.66M) over dead qkv splits
  const size_t WB_BYTES = 50331648;
  unsigned short* Wb = (unsigned short*)d_ws;
  unsigned short* qh = (unsigned short*)((char*)d_ws + WB_BYTES);
  unsigned short* ql = qh + 4194304;
  unsigned short* kh = ql + 4194304;
  unsigned short* kl = kh + 4194304;
  unsigned short* vv = kl + 4194304;
  float* AO = (float*)d_ws;
  float* P  = (float*)((char*)d_ws + WB_BYTES);
  int* flag = (int*)d_out;   // dead until reduce overwrites it

  wcvt_kernel<<<dim3(1024, 4), 256, 0, stream>>>(q_w, k_w, v_w, o_w, Wb, flag);
  amask_scan<<<1024, 256, 0, stream>>>(amask, flag);
  conv_mfma6<0><<<dim3(8, 32, 3), 256, 0, stream>>>(
      query, key_, value, Wb, q_b, k_b, v_b, qh, ql, kh, kl, vv, nullptr);
  attn_mfma3<<<1024, 256, 0, stream>>>(qh, ql, kh, kl, vv, kpm, amask, flag, AO);
  conv_mfma6<1><<<dim3(8, 32, 3), 256, 0, stream>>>(
      AO, nullptr, nullptr, Wb + (size_t)3 * 6 * (1u << 20),
      nullptr, nullptr, nullptr, nullptr, nullptr, nullptr, nullptr, nullptr, P);
  reduce_kernel<<<4096, 256, 0, stream>>>(P, o_b, out);
}

// Round 10
// 511.911 us; speedup vs baseline: 1.0449x; 1.0449x over previous
//
#include <hip/hip_runtime.h>
#include <math.h>

#define NB 4
#define NL 1024
#define ND 1024
#define NH 16
#define HD 64

typedef __attribute__((ext_vector_type(8))) short bf16x8;
typedef __attribute__((ext_vector_type(4))) float f32x4;

static __device__ __forceinline__ unsigned short f32_to_bf16(float f) {
  unsigned u = __float_as_uint(f);
  u += 0x7FFFu + ((u >> 16) & 1u);   // RNE
  return (unsigned short)(u >> 16);
}
static __device__ __forceinline__ float bf16_to_f32(unsigned short s) {
  return __uint_as_float(((unsigned)s) << 16);
}
// trunc-split: x = hi + lo + O(2^-17 |x|)
static __device__ __forceinline__ void split1(float x, unsigned short* h, unsigned short* l) {
  unsigned u = __float_as_uint(x);
  *h = (unsigned short)(u >> 16);
  float r = x - __uint_as_float(u & 0xFFFF0000u);
  *l = (unsigned short)(__float_as_uint(r) >> 16);
}
static __device__ __forceinline__ void split8(float4 a, float4 b, bf16x8* hi, bf16x8* lo) {
  unsigned u[8] = {__float_as_uint(a.x), __float_as_uint(a.y),
                   __float_as_uint(a.z), __float_as_uint(a.w),
                   __float_as_uint(b.x), __float_as_uint(b.y),
                   __float_as_uint(b.z), __float_as_uint(b.w)};
  union { unsigned p[4]; bf16x8 v; } H, L;
#pragma unroll
  for (int p = 0; p < 4; ++p) {
    unsigned u0 = u[2 * p], u1 = u[2 * p + 1];
    H.p[p] = __builtin_amdgcn_perm(u1, u0, 0x07060302u);
    unsigned l0 = __float_as_uint(__uint_as_float(u0) - __uint_as_float(u0 & 0xFFFF0000u));
    unsigned l1 = __float_as_uint(__uint_as_float(u1) - __uint_as_float(u1 & 0xFFFF0000u));
    L.p[p] = __builtin_amdgcn_perm(l1, l0, 0x07060302u);
  }
  *hi = H.v; *lo = L.v;
}

// ---------------- weight convert: w[o][i][k] -> Wb hi/lo [koff][o][i] bf16 ----------------
__global__ __launch_bounds__(256) void wcvt_kernel(
    const float* __restrict__ w0, const float* __restrict__ w1,
    const float* __restrict__ w2, const float* __restrict__ w3,
    unsigned short* __restrict__ wb, int* __restrict__ flag)
{
  if (blockIdx.x == 0 && blockIdx.y == 0 && threadIdx.x == 0) flag[0] = 0;
  const int t = blockIdx.y;
  const int o = blockIdx.x;
  const float* w = (t == 0) ? w0 : (t == 1) ? w1 : (t == 2) ? w2 : w3;
  unsigned short* hi = wb + (size_t)t * 6 * (1u << 20);
  unsigned short* lo = hi + 3 * (1u << 20);
  const int tid = threadIdx.x;
  float v[12];
  const float* src = w + (size_t)o * (ND * 3) + tid * 12;
#pragma unroll
  for (int j = 0; j < 3; ++j) {
    float4 f = *(const float4*)(src + j * 4);
    v[j * 4 + 0] = f.x; v[j * 4 + 1] = f.y; v[j * 4 + 2] = f.z; v[j * 4 + 3] = f.w;
  }
#pragma unroll
  for (int k = 0; k < 3; ++k) {
    unsigned short hh[4], ll[4];
#pragma unroll
    for (int ii = 0; ii < 4; ++ii) {
      float x = v[ii * 3 + k];
      unsigned short h = f32_to_bf16(x);
      float r = x - bf16_to_f32(h);
      hh[ii] = h; ll[ii] = f32_to_bf16(r);
    }
    size_t dst = (size_t)k * (ND * ND) + (size_t)o * ND + tid * 4;
    *(ushort4*)&hi[dst] = make_ushort4(hh[0], hh[1], hh[2], hh[3]);
    *(ushort4*)&lo[dst] = make_ushort4(ll[0], ll[1], ll[2], ll[3]);
  }
}

// ---------------- amask zero-scan ----------------
__global__ __launch_bounds__(256) void amask_scan(
    const float* __restrict__ a, int* __restrict__ flag)
{
  size_t i = ((size_t)blockIdx.x * 256 + threadIdx.x) * 4;
  float4 v = *(const float4*)&a[i];
  if (v.x != 0.f || v.y != 0.f || v.z != 0.f || v.w != 0.f) atomicOr(flag, 1);
}

// ---------------- conv-as-GEMM: R5-proven loop, 16x16x32 ----------------
// MODE 0: z = tensor (q/k/v), koff 0..2; A = fp32 inputs (clamp + edge-fix);
//         epilogue: z0 -> qh/ql (scaled), z1 -> kh/kl  [B,H,L,HD]; z2 -> vt [B,H,HD,L]
// MODE 1: z = koff (split-K o-conv); A = fp32 padded AO [B,1026,D]; fp32 partials P[z]
template <int MODE>
__global__ __launch_bounds__(256, 3) void conv_mfma7(
    const float* __restrict__ X0, const float* __restrict__ X1,
    const float* __restrict__ X2,
    const unsigned short* __restrict__ wb,
    const float* b0, const float* b1, const float* b2,
    unsigned short* qh, unsigned short* ql,
    unsigned short* kh, unsigned short* kl, unsigned short* vt,
    float* P)
{
  __shared__ __align__(16) float Af[4096];            // 16KB fp32 A tile
  __shared__ __align__(16) unsigned short Bh[4096];   // 8KB
  __shared__ __align__(16) unsigned short Bl[4096];   // 8KB

  const int tid = threadIdx.x, lane = tid & 63, wave = tid >> 6;
  const int lin = blockIdx.x + 8 * (blockIdx.y + 32 * blockIdx.z);
  const int g = lin & 7, t = lin >> 3;
  const int nb = (g & 3) * 2 + (t & 1);
  const int mb = (g >> 2) * 16 + ((t >> 1) & 15);
  const int z  = t >> 5;
  const int n0 = nb * 128, m0 = mb * 128;
  const int b = m0 >> 10, l0v = m0 & (NL - 1);

  const unsigned short* Wh = (MODE == 0) ? wb + (size_t)z * 6 * (1u << 20) : wb;
  const unsigned short* Wl = Wh + 3 * (1u << 20);
  const float* X = (MODE == 0) ? (z == 0 ? X0 : (z == 1 ? X1 : X2)) : X0;

  const int wm = (wave >> 1) * 64, wn = (wave & 1) * 64;
  const int mrow = lane & 15, quad = lane >> 4;
  const int r16 = lane >> 2, cs = lane & 3;
  const int src_chunk = (cs - (r16 >> 1)) & 3;      // B global-side granule swizzle
  const int bswz = ((quad + (mrow >> 1)) & 3) * 8;  // B frag-read swizzle

  f32x4 acc[4][4] = {};
  const int NS = (MODE == 0) ? 96 : 32;             // (koff) x (i0/32)

  for (int s = 0; s < NS; ++s) {
    const int koff = (MODE == 0) ? (s >> 5) : z;
    const int i0 = (s & 31) * 32;
    // ---- B staging (async, swizzled) ----
#pragma unroll
    for (int j = 0; j < 2; ++j) {
      const int seg = wave * 2 + j;
      const size_t gw = ((size_t)koff << 20) +
                        (size_t)(n0 + seg * 16 + r16) * ND + i0 + src_chunk * 8;
      __builtin_amdgcn_global_load_lds(
          (const __attribute__((address_space(1))) unsigned int*)(Wh + gw),
          (__attribute__((address_space(3))) unsigned int*)&Bh[seg * 512], 16, 0, 0);
      __builtin_amdgcn_global_load_lds(
          (const __attribute__((address_space(1))) unsigned int*)(Wl + gw),
          (__attribute__((address_space(3))) unsigned int*)&Bl[seg * 512], 16, 0, 0);
    }
    // ---- A staging: fp32 async, row-chunk swizzle ----
#pragma unroll
    for (int j = 0; j < 4; ++j) {
      const int sl = (wave * 4 + j) * 64 + lane;
      const int row = sl >> 3, sir = sl & 7;
      const int chunk = (sir - (row & 7)) & 7;
      const float* gp;
      if (MODE == 0) {
        int l = l0v + row + koff - 1;
        l = (l < 0) ? 0 : (l > NL - 1 ? NL - 1 : l);   // clamp; edge zero-fix below
        gp = X + ((size_t)(b << 10) + l) * ND + i0 + chunk * 4;
      } else {
        gp = X + (size_t)(b * 1026 + l0v + z + row) * ND + i0 + chunk * 4;
      }
      __builtin_amdgcn_global_load_lds(
          (const __attribute__((address_space(1))) unsigned int*)gp,
          (__attribute__((address_space(3))) unsigned int*)&Af[(wave * 4 + j) * 256],
          16, 0, 0);
    }
    __syncthreads();
    if (MODE == 0) {
      const bool e_lo = (l0v == 0 && koff == 0);
      const bool e_hi = (l0v == NL - 128 && koff == 2);
      if (e_lo || e_hi) {                 // block-uniform; 2 blocks per z only
        const int er = e_lo ? 0 : 127;
        if (tid < 8) *(float4*)&Af[er * 32 + tid * 4] = make_float4(0.f, 0.f, 0.f, 0.f);
        __syncthreads();
      }
    }
    // ---- fragments + split + MFMA (48 / wave / step) ----
    bf16x8 ah[4], al[4];
#pragma unroll
    for (int mi = 0; mi < 4; ++mi) {
      const int row = wm + mi * 16 + mrow, r7 = row & 7;
      float4 fa = *(const float4*)&Af[row * 32 + (((quad * 2) + r7) & 7) * 4];
      float4 fb = *(const float4*)&Af[row * 32 + (((quad * 2 + 1) + r7) & 7) * 4];
      split8(fa, fb, &ah[mi], &al[mi]);
    }
#pragma unroll
    for (int ni = 0; ni < 4; ++ni) {
      const int brow = wn + ni * 16 + mrow;
      bf16x8 bh = *(const bf16x8*)&Bh[brow * 32 + bswz];
      bf16x8 bl = *(const bf16x8*)&Bl[brow * 32 + bswz];
#pragma unroll
      for (int mi = 0; mi < 4; ++mi) {
        acc[mi][ni] = __builtin_amdgcn_mfma_f32_16x16x32_bf16(ah[mi], bh, acc[mi][ni], 0, 0, 0);
        acc[mi][ni] = __builtin_amdgcn_mfma_f32_16x16x32_bf16(ah[mi], bl, acc[mi][ni], 0, 0, 0);
        acc[mi][ni] = __builtin_amdgcn_mfma_f32_16x16x32_bf16(al[mi], bh, acc[mi][ni], 0, 0, 0);
      }
    }
    __syncthreads();
  }

  // ---- epilogue ----
  if (MODE == 0) {
    const float* bias = (z == 0) ? b0 : (z == 1) ? b1 : b2;
#pragma unroll
    for (int ni = 0; ni < 4; ++ni) {
      const int n = n0 + wn + ni * 16 + mrow;
      const float bv = bias[n];
      const int h2 = n >> 6, dd = n & 63;
#pragma unroll
      for (int mi = 0; mi < 4; ++mi) {
        const int mbase = m0 + wm + mi * 16 + quad * 4;
        const int lb = mbase & (NL - 1);
        f32x4 v = acc[mi][ni];
        if (z == 2) {
          // V^T: [B,H,dd,L] — 4 contiguous shorts (8B store)
          ushort4 pk;
          pk.x = f32_to_bf16(v[0] + bv); pk.y = f32_to_bf16(v[1] + bv);
          pk.z = f32_to_bf16(v[2] + bv); pk.w = f32_to_bf16(v[3] + bv);
          *(ushort4*)&vt[(((size_t)b * NH + h2) * HD + dd) * NL + lb] = pk;
        } else {
#pragma unroll
          for (int r = 0; r < 4; ++r) {
            const size_t o = (((size_t)b * NH + h2) * NL + (lb + r)) * HD + dd;
            float val = v[r] + bv;
            if (z == 0) {
              val *= 0.125f;
              unsigned short hs, ls; split1(val, &hs, &ls);
              qh[o] = hs; ql[o] = ls;
            } else {
              unsigned short hs, ls; split1(val, &hs, &ls);
              kh[o] = hs; kl[o] = ls;
            }
          }
        }
      }
    }
  } else {
    float* Pz = P + (size_t)z * ((size_t)NB * NL * ND);
#pragma unroll
    for (int ni = 0; ni < 4; ++ni) {
      const int n = n0 + wn + ni * 16 + mrow;
#pragma unroll
      for (int mi = 0; mi < 4; ++mi) {
        const int mbase = m0 + wm + mi * 16 + quad * 4;
        f32x4 v = acc[mi][ni];
#pragma unroll
        for (int r = 0; r < 4; ++r) {
          const int l = (mbase + r) & (NL - 1);
          Pz[((size_t)(b << 10) + l) * ND + n] = v[r];
        }
      }
    }
  }
}

// ---------------- reduce: out = P0 + P1 + P2 + bias ----------------
__global__ __launch_bounds__(256) void reduce_kernel(
    const float* __restrict__ P, const float* __restrict__ bias, float* __restrict__ out)
{
  const size_t S = (size_t)NB * NL * ND;
  const size_t idx = ((size_t)blockIdx.x * 256 + threadIdx.x) * 4;
  const int n = (int)(idx & (ND - 1));
  float4 p0 = *(const float4*)&P[idx];
  float4 p1 = *(const float4*)&P[idx + S];
  float4 p2 = *(const float4*)&P[idx + 2 * S];
  float4 bv = *(const float4*)&bias[n];
  float4 r;
  r.x = p0.x + p1.x + p2.x + bv.x;
  r.y = p0.y + p1.y + p2.y + bv.y;
  r.z = p0.z + p1.z + p2.z + bv.z;
  r.w = p0.w + p1.w + p2.w + bv.w;
  *(float4*)&out[idx] = r;
}

// ---------------- MFMA flash attention (V^T pre-transposed; all staging async) ----------------
__global__ __launch_bounds__(256, 3) void attn_mfma4(
    const unsigned short* __restrict__ qhp, const unsigned short* __restrict__ qlp,
    const unsigned short* __restrict__ khp, const unsigned short* __restrict__ klp,
    const unsigned short* __restrict__ vtp, const int* __restrict__ kpm,
    const float* __restrict__ amask, const int* __restrict__ aflagp,
    float* __restrict__ AO)
{
  __shared__ __align__(16) unsigned short SM[3 * 4096];  // Kh | Kl | Vt (stride 64 each)
  unsigned short* Kh = SM;
  unsigned short* Kl = SM + 4096;
  unsigned short* Vt = SM + 8192;

  const int tid = threadIdx.x, lane = tid & 63, wave = tid >> 6;
  const int c = lane & 15, quad = lane >> 4;
  const int lin = blockIdx.x;
  const int bh_ = (lin & 7) + 8 * (lin >> 7);
  const int mt = (lin >> 3) & 15;
  const int b = bh_ >> 4, h = bh_ & 15;
  const int m0 = mt * 64;
  const size_t base = (size_t)bh_ * (NL * HD);   // q/k layout [B,H,L,HD]
  const size_t vbase = (size_t)bh_ * (HD * NL);  // v layout [B,H,HD,L]
  const int aflag = *aflagp;
  const int mrow = wave * 16 + c;
  const int gm = m0 + mrow;

  // zero fp32 AO pad rows (consumed only by the o-conv)
  if (h == 0 && mt == 0)
    *(float4*)&AO[(size_t)(b * 1026) * ND + tid * 4] = make_float4(0.f, 0.f, 0.f, 0.f);
  if (h == 0 && mt == 15)
    *(float4*)&AO[((size_t)(b * 1026) + 1025) * ND + tid * 4] = make_float4(0.f, 0.f, 0.f, 0.f);

  const int rowo = lane >> 3;
  const int grano = ((lane & 7) - rowo) & 7;      // granule swizzle: slot = (g + row)&7

  // ---- stage Q into Kh/Kl, pull B-frags ----
#pragma unroll
  for (int j = 0; j < 2; ++j) {
    const int s = wave * 2 + j;
    const size_t go = base + (size_t)(m0 + s * 8 + rowo) * HD + grano * 8;
    __builtin_amdgcn_global_load_lds(
        (const __attribute__((address_space(1))) unsigned int*)(qhp + go),
        (__attribute__((address_space(3))) unsigned int*)&Kh[s * 512], 16, 0, 0);
    __builtin_amdgcn_global_load_lds(
        (const __attribute__((address_space(1))) unsigned int*)(qlp + go),
        (__attribute__((address_space(3))) unsigned int*)&Kl[s * 512], 16, 0, 0);
  }
  __syncthreads();
  bf16x8 qbh[2], qbl[2];
#pragma unroll
  for (int kb = 0; kb < 2; ++kb) {
    const int cso = ((kb * 4 + quad + mrow) & 7) * 8;
    qbh[kb] = *(const bf16x8*)&Kh[mrow * 64 + cso];
    qbl[kb] = *(const bf16x8*)&Kl[mrow * 64 + cso];
  }

  f32x4 acc[4] = {};
  float m_r = -INFINITY, l_r = 0.0f;

  for (int n0t = 0; n0t < NL; n0t += 64) {
    __syncthreads();

    // masks for this lane's 16 score slots
    float mval[4][4];
#pragma unroll
    for (int nf = 0; nf < 4; ++nf) {
      int4 pm4 = *(const int4*)&kpm[b * NL + n0t + nf * 16 + quad * 4];
      const int* pmi = &pm4.x;
#pragma unroll
      for (int r = 0; r < 4; ++r) {
        float am = 0.f;
        if (aflag) am = amask[(size_t)gm * NL + (n0t + nf * 16 + quad * 4 + r)];
        mval[nf][r] = pmi[r] ? -INFINITY : am;
      }
    }

    // ---- stage K rows [j][dd] and V^T rows [dd][j] — all async ----
#pragma unroll
    for (int j = 0; j < 2; ++j) {
      const int s = wave * 2 + j;
      const size_t go = base + (size_t)(n0t + s * 8 + rowo) * HD + grano * 8;
      __builtin_amdgcn_global_load_lds(
          (const __attribute__((address_space(1))) unsigned int*)(khp + go),
          (__attribute__((address_space(3))) unsigned int*)&Kh[s * 512], 16, 0, 0);
      __builtin_amdgcn_global_load_lds(
          (const __attribute__((address_space(1))) unsigned int*)(klp + go),
          (__attribute__((address_space(3))) unsigned int*)&Kl[s * 512], 16, 0, 0);
      const size_t gv = vbase + (size_t)(s * 8 + rowo) * NL + n0t + grano * 8;
      __builtin_amdgcn_global_load_lds(
          (const __attribute__((address_space(1))) unsigned int*)(vtp + gv),
          (__attribute__((address_space(3))) unsigned int*)&Vt[s * 512], 16, 0, 0);
    }
    __syncthreads();

    // ---- St = K·Q^T (3-MFMA split) ----
    f32x4 sa[4] = {};
#pragma unroll
    for (int kb = 0; kb < 2; ++kb)
#pragma unroll
      for (int nf = 0; nf < 4; ++nf) {
        const int row = nf * 16 + c;
        const int cso = ((kb * 4 + quad + row) & 7) * 8;
        bf16x8 kah = *(const bf16x8*)&Kh[row * 64 + cso];
        bf16x8 kal = *(const bf16x8*)&Kl[row * 64 + cso];
        sa[nf] = __builtin_amdgcn_mfma_f32_16x16x32_bf16(kah, qbh[kb], sa[nf], 0, 0, 0);
        sa[nf] = __builtin_amdgcn_mfma_f32_16x16x32_bf16(kah, qbl[kb], sa[nf], 0, 0, 0);
        sa[nf] = __builtin_amdgcn_mfma_f32_16x16x32_bf16(kal, qbh[kb], sa[nf], 0, 0, 0);
      }

    // ---- online softmax in registers ----
    float p[4][4];
    float tmax = -INFINITY;
#pragma unroll
    for (int nf = 0; nf < 4; ++nf)
#pragma unroll
      for (int r = 0; r < 4; ++r) {
        float s = sa[nf][r] + mval[nf][r];
        p[nf][r] = s;
        tmax = fmaxf(tmax, s);
      }
    tmax = fmaxf(tmax, __shfl_xor(tmax, 16));
    tmax = fmaxf(tmax, __shfl_xor(tmax, 32));
    const float newm = fmaxf(m_r, tmax);
    const float msafe = (newm == -INFINITY) ? 0.f : newm;
    const float alpha = __expf(m_r - msafe);
    float rs = 0.f;
#pragma unroll
    for (int nf = 0; nf < 4; ++nf)
#pragma unroll
      for (int r = 0; r < 4; ++r) {
        float e = __expf(p[nf][r] - msafe);
        p[nf][r] = e;
        rs += e;
      }
    rs += __shfl_xor(rs, 16);
    rs += __shfl_xor(rs, 32);
    l_r = l_r * alpha + rs;
    m_r = newm;
#pragma unroll
    for (int df = 0; df < 4; ++df) {
      acc[df][0] *= alpha; acc[df][1] *= alpha;
      acc[df][2] *= alpha; acc[df][3] *= alpha;
    }

    // ---- pack P, bpermute to B-layout, O^T += V^T·P^T ----
    unsigned q16[4][2];
#pragma unroll
    for (int nf = 0; nf < 4; ++nf)
#pragma unroll
      for (int w = 0; w < 2; ++w)
        q16[nf][w] = (unsigned)f32_to_bf16(p[nf][2 * w]) |
                     ((unsigned)f32_to_bf16(p[nf][2 * w + 1]) << 16);
#pragma unroll
    for (int kb = 0; kb < 2; ++kb) {
      union { unsigned d[4]; bf16x8 v; } pb;
#pragma unroll
      for (int w = 0; w < 4; ++w) {
        const int addr = ((((quad & 1) * 2 + (w >> 1)) * 16 + c) << 2);
        unsigned v0 = __builtin_amdgcn_ds_bpermute(addr, (int)q16[2 * kb][w & 1]);
        unsigned v1 = __builtin_amdgcn_ds_bpermute(addr, (int)q16[2 * kb + 1][w & 1]);
        pb.d[w] = (quad >> 1) ? v1 : v0;
      }
#pragma unroll
      for (int df = 0; df < 4; ++df) {
        const int row = df * 16 + c;
        const int cso = ((kb * 4 + quad + row) & 7) * 8;
        bf16x8 va = *(const bf16x8*)&Vt[row * 64 + cso];
        acc[df] = __builtin_amdgcn_mfma_f32_16x16x32_bf16(va, pb.v, acc[df], 0, 0, 0);
      }
    }
  }

  // ---- epilogue: transpose O^T -> O via LDS, coalesced fp32 padded store ----
  __syncthreads();
  const float inv = 1.0f / l_r;
  float* Ob = (float*)SM + wave * (16 * 68);   // 17408B < 24KB SM
#pragma unroll
  for (int df = 0; df < 4; ++df)
#pragma unroll
    for (int r = 0; r < 4; ++r)
      Ob[c * 68 + df * 16 + quad * 4 + r] = acc[df][r] * inv;
  __syncthreads();
  const int mr2 = lane >> 2, cq2 = lane & 3;
#pragma unroll
  for (int ii = 0; ii < 4; ++ii) {
    const int chunk = cq2 * 4 + ii;
    float4 v = *(const float4*)&Ob[mr2 * 68 + chunk * 4];
    *(float4*)&AO[((size_t)(b * 1026) + (m0 + wave * 16 + mr2) + 1) * ND +
                  h * HD + chunk * 4] = v;
  }
}

// ---------------- launch ----------------
extern "C" void kernel_launch(void* const* d_in, const int* in_sizes, int n_in,
                              void* d_out, int out_size, void* d_ws, size_t ws_size,
                              hipStream_t stream) {
  (void)in_sizes; (void)n_in; (void)out_size; (void)ws_size;
  const float* query = (const float*)d_in[0];
  const float* key_  = (const float*)d_in[1];
  const float* value = (const float*)d_in[2];
  const int*   kpm   = (const int*)d_in[3];
  const float* amask = (const float*)d_in[4];
  const float* q_w = (const float*)d_in[5];
  const float* q_b = (const float*)d_in[6];
  const float* k_w = (const float*)d_in[7];
  const float* k_b = (const float*)d_in[8];
  const float* v_w = (const float*)d_in[9];
  const float* v_b = (const float*)d_in[10];
  const float* o_w = (const float*)d_in[11];
  const float* o_b = (const float*)d_in[12];
  float* out = (float*)d_out;

  // ws layout (max offset 100.66 MB, proven since R1):
  //  [0, 50.33M): Wb (4 tensors hi/lo bf16)
  //  [50.33M, 92.27M): qh/ql/kh/kl/vt bf16 (dead after attn)
  //  AO fp32 padded [B,1026,D] at [0, 16.81M) over dead Wb q/k slabs (Wb_o untouched)
  //  P fp32 [50.33M, 100.66M) over dead qkv splits
  const size_t WB_BYTES = 50331648;
  unsigned short* Wb = (unsigned short*)d_ws;
  unsigned short* qh = (unsigned short*)((char*)d_ws + WB_BYTES);
  unsigned short* ql = qh + 4194304;
  unsigned short* kh = ql + 4194304;
  unsigned short* kl = kh + 4194304;
  unsigned short* vt = kl + 4194304;
  float* AO = (float*)d_ws;
  float* P  = (float*)((char*)d_ws + WB_BYTES);
  int* flag = (int*)d_out;   // dead until reduce overwrites it

  wcvt_kernel<<<dim3(1024, 4), 256, 0, stream>>>(q_w, k_w, v_w, o_w, Wb, flag);
  amask_scan<<<1024, 256, 0, stream>>>(amask, flag);
  conv_mfma7<0><<<dim3(8, 32, 3), 256, 0, stream>>>(
      query, key_, value, Wb, q_b, k_b, v_b, qh, ql, kh, kl, vt, nullptr);
  attn_mfma4<<<1024, 256, 0, stream>>>(qh, ql, kh, kl, vt, kpm, amask, flag, AO);
  conv_mfma7<1><<<dim3(8, 32, 3), 256, 0, stream>>>(
      AO, nullptr, nullptr, Wb + (size_t)3 * 6 * (1u << 20),
      nullptr, nullptr, nullptr, nullptr, nullptr, nullptr, nullptr, nullptr, P);
  reduce_kernel<<<4096, 256, 0, stream>>>(P, o_b, out);
}